// Round 1
// baseline (520.908 us; speedup 1.0000x reference)
//
#include <hip/hip_runtime.h>
#include <math.h>

#define B 4
#define C 64
#define H 128
#define W 128
#define KK 9
#define CENTER 4
#define NOFF 10          // offset channels actually needed (0..8 + ch9 for GN group 4 stats)
#define HW (H*W)         // 16384

// ---------------- workspace layout (in floats) ----------------
#define OFF_OFF    0                       // B*NOFF*HW = 655360
#define OFF_OSTATS 655360                  // B*5*2 = 40
#define OFF_WT     655424                  // KK*C*C = 36864  (aligned 16B)
#define OFF_CSUM   692288                  // B*C*2 = 512
#define OFF_GNP    692800                  // B*C*2 = 512
// total 693312 floats = 2.78 MB

// ---- K0: transpose w_dsc [co][ci][k] -> wT [k][ci][co] (co contiguous) ----
__global__ __launch_bounds__(256) void k_transpose(const float* __restrict__ w,
                                                   float* __restrict__ wT) {
    int idx = blockIdx.x * 256 + threadIdx.x;
    if (idx < C * C * KK) {
        int co = idx / (C * KK);
        int r  = idx - co * C * KK;
        int ci = r / KK;
        int k  = r - ci * KK;
        wT[(k * C + ci) * C + co] = w[idx];
    }
}

// ---- K1: 3x3 SAME conv, x(64ch) -> off(10ch), +bias ----
__global__ __launch_bounds__(256) void k_offconv(const float* __restrict__ x,
                                                 const float* __restrict__ w_off,
                                                 const float* __restrict__ b_off,
                                                 float* __restrict__ off) {
    int bid = blockIdx.x;          // 256 blocks: b(4) x ty(8) x tx(8)
    int b  = bid >> 6;
    int ty = (bid >> 3) & 7, tx = bid & 7;
    int h0 = ty * 16, w0 = tx * 16;
    int tid = threadIdx.x;
    int lh = tid >> 4, lw = tid & 15;

    __shared__ float lx[16 * 18 * 18];   // [ci_local][y][x], 20.7 KB

    float acc[NOFF];
#pragma unroll
    for (int j = 0; j < NOFF; j++) acc[j] = 0.f;

    for (int cc = 0; cc < 4; cc++) {     // 4 chunks of 16 input channels
        __syncthreads();
        for (int i = tid; i < 16 * 324; i += 256) {
            int ci = i / 324;
            int r  = i - ci * 324;
            int y  = r / 18;
            int xx = r - y * 18;
            int gy = h0 + y - 1, gx = w0 + xx - 1;
            float v = 0.f;
            if (gy >= 0 && gy < H && gx >= 0 && gx < W)
                v = x[(((b * C) + (cc * 16 + ci)) * H + gy) * W + gx];
            lx[i] = v;
        }
        __syncthreads();

        for (int cl = 0; cl < 16; cl++) {
            int ci = cc * 16 + cl;
            float xv[9];
#pragma unroll
            for (int ky = 0; ky < 3; ky++)
#pragma unroll
                for (int kx = 0; kx < 3; kx++)
                    xv[ky * 3 + kx] = lx[(cl * 18 + lh + ky) * 18 + lw + kx];
#pragma unroll
            for (int j = 0; j < NOFF; j++) {
                const float* wp = w_off + (j * C + ci) * 9;   // uniform -> s_load
#pragma unroll
                for (int t = 0; t < 9; t++) acc[j] += wp[t] * xv[t];
            }
        }
    }

    int h = h0 + lh, w = w0 + lw;
#pragma unroll
    for (int j = 0; j < NOFF; j++)
        off[((b * NOFF + j) * H + h) * W + w] = acc[j] + b_off[j];
}

// ---- K2: GN stats for offsets: groups of 2 channels, 20 (b,g) blocks ----
__global__ __launch_bounds__(256) void k_ostats(const float* __restrict__ off,
                                                float* __restrict__ ostats) {
    int b = blockIdx.x / 5, g = blockIdx.x % 5;
    int tid = threadIdx.x;
    float s = 0.f, s2 = 0.f;
    const float* p0 = off + ((size_t)(b * NOFF + 2 * g) * HW); // ch 2g,2g+1 contiguous
    for (int i = tid; i < 2 * HW; i += 256) {
        float v = p0[i];
        s += v; s2 += v * v;
    }
    __shared__ float rs[256], rq[256];
    rs[tid] = s; rq[tid] = s2;
    __syncthreads();
    for (int st = 128; st > 0; st >>= 1) {
        if (tid < st) { rs[tid] += rs[tid + st]; rq[tid] += rq[tid + st]; }
        __syncthreads();
    }
    if (tid == 0) {
        float n = 2.f * HW;
        float mean = rs[0] / n;
        float var  = rq[0] / n - mean * mean;
        ostats[(b * 5 + g) * 2]     = mean;
        ostats[(b * 5 + g) * 2 + 1] = rsqrtf(var + 1e-5f);
    }
}

// ---- K4: fused tanh+cumsum+resample + 9x1 stride-9 conv + stat partials ----
__global__ __launch_bounds__(256) void k_main(const float* __restrict__ x,
                                              const float* __restrict__ off,
                                              const float* __restrict__ ostats,
                                              const float* __restrict__ g_gn_off,
                                              const float* __restrict__ b_gn_off,
                                              const float* __restrict__ wT,
                                              const float* __restrict__ b_dsc,
                                              float* __restrict__ outp,
                                              float* __restrict__ csum) {
    int bid = blockIdx.x;            // 256 blocks: b(4) x rowpair(64)
    int b  = bid >> 6;
    int rp = bid & 63;
    int tid = threadIdx.x;
    int h = rp * 2 + (tid >> 7);
    int w = tid & 127;

    // normalized+tanh offset channels
    float v[KK];
#pragma unroll
    for (int j = 0; j < KK; j++) {
        float o = off[((b * NOFF + j) * H + h) * W + w];
        int g = j >> 1;
        float mean = ostats[(b * 5 + g) * 2];
        float rstd = ostats[(b * 5 + g) * 2 + 1];
        v[j] = tanhf((o - mean) * rstd * g_gn_off[j] + b_gn_off[j]);
    }
    // channel cumsum away from center
    float yoff[KK];
    yoff[CENTER] = 0.f;
    {
        float run = 0.f;
#pragma unroll
        for (int k = CENTER - 1; k >= 0; k--) { run += v[k]; yoff[k] = run; }
    }
    {
        float run = 0.f;
#pragma unroll
        for (int k = CENTER + 1; k < KK; k++) { run += v[k]; yoff[k] = run; }
    }

    float acc[C];
#pragma unroll
    for (int i = 0; i < C; i++) acc[i] = 0.f;

    const float* xb = x + (size_t)b * C * HW;

#pragma unroll
    for (int k = 0; k < KK; k++) {
        float yc = fminf(fmaxf((float)h + yoff[k], 0.f), (float)(H - 1));
        float fy = floorf(yc);
        float wy = yc - fy;
        int y0 = (int)fy;
        int y1 = min(y0 + 1, H - 1);
        int xi = min(max(w + k - CENTER, 0), W - 1);
        const float* p0 = xb + y0 * W + xi;
        const float* p1 = xb + y1 * W + xi;
        float w1 = wy, w0c = 1.f - wy;
#pragma unroll 2
        for (int ci = 0; ci < C; ci++) {
            float s = w0c * p0[(size_t)ci * HW] + w1 * p1[(size_t)ci * HW];
            const float4* wt4 = (const float4*)(wT + ((k * C + ci) << 6)); // uniform
#pragma unroll
            for (int q = 0; q < 16; q++) {
                float4 wv = wt4[q];
                acc[q * 4 + 0] += wv.x * s;
                acc[q * 4 + 1] += wv.y * s;
                acc[q * 4 + 2] += wv.z * s;
                acc[q * 4 + 3] += wv.w * s;
            }
        }
    }

    int lane = tid & 63;
    float* myout = outp + (size_t)(b * C) * HW + h * W + w;
#pragma unroll
    for (int co = 0; co < C; co++) {
        float val = acc[co] + b_dsc[co];
        myout[(size_t)co * HW] = val;
        float sv = val, sq = val * val;
#pragma unroll
        for (int o = 32; o >= 1; o >>= 1) {
            sv += __shfl_xor(sv, o);
            sq += __shfl_xor(sq, o);
        }
        if (lane == 0) {
            atomicAdd(&csum[(b * C + co) * 2],     sv);
            atomicAdd(&csum[(b * C + co) * 2 + 1], sq);
        }
    }
}

// ---- K5: finalize GN params: scale/shift per (b,co) ----
__global__ __launch_bounds__(256) void k_fin(const float* __restrict__ csum,
                                             const float* __restrict__ g_gn,
                                             const float* __restrict__ b_gn,
                                             float* __restrict__ gnp) {
    int t = threadIdx.x;             // 256 == B*C
    int b = t >> 6, co = t & 63;
    int grp = co >> 2;
    float S = 0.f, S2 = 0.f;
#pragma unroll
    for (int c2 = 0; c2 < 4; c2++) {
        S  += csum[(b * C + grp * 4 + c2) * 2];
        S2 += csum[(b * C + grp * 4 + c2) * 2 + 1];
    }
    float n = 4.f * HW;
    float mean = S / n;
    float var  = S2 / n - mean * mean;
    float rstd = rsqrtf(var + 1e-5f);
    float sc = rstd * g_gn[co];
    gnp[(b * C + co) * 2]     = sc;
    gnp[(b * C + co) * 2 + 1] = b_gn[co] - mean * sc;
}

// ---- K6: in-place GN apply + ReLU on d_out ----
__global__ __launch_bounds__(256) void k_norm(float* __restrict__ outp,
                                              const float* __restrict__ gnp) {
    int idx = blockIdx.x * 256 + threadIdx.x;   // B*C*HW/4 float4s
    float4* p = (float4*)outp;
    float4 vv = p[idx];
    int bc = (idx * 4) >> 14;                    // b*C+co (HW multiple of 4)
    float sc = gnp[bc * 2], sh = gnp[bc * 2 + 1];
    vv.x = fmaxf(vv.x * sc + sh, 0.f);
    vv.y = fmaxf(vv.y * sc + sh, 0.f);
    vv.z = fmaxf(vv.z * sc + sh, 0.f);
    vv.w = fmaxf(vv.w * sc + sh, 0.f);
    p[idx] = vv;
}

extern "C" void kernel_launch(void* const* d_in, const int* in_sizes, int n_in,
                              void* d_out, int out_size, void* d_ws, size_t ws_size,
                              hipStream_t stream) {
    const float* x        = (const float*)d_in[0];
    const float* w_off    = (const float*)d_in[1];
    const float* b_off    = (const float*)d_in[2];
    const float* g_gn_off = (const float*)d_in[3];
    const float* b_gn_off = (const float*)d_in[4];
    const float* w_dsc    = (const float*)d_in[5];
    const float* b_dsc    = (const float*)d_in[6];
    const float* g_gn     = (const float*)d_in[7];
    const float* b_gn     = (const float*)d_in[8];
    float* out = (float*)d_out;
    float* ws  = (float*)d_ws;

    float* off    = ws + OFF_OFF;
    float* ostats = ws + OFF_OSTATS;
    float* wT     = ws + OFF_WT;
    float* csum   = ws + OFF_CSUM;
    float* gnp    = ws + OFF_GNP;

    hipMemsetAsync(csum, 0, 2 * B * C * sizeof(float), stream);
    k_transpose<<<(C * C * KK + 255) / 256, 256, 0, stream>>>(w_dsc, wT);
    k_offconv<<<256, 256, 0, stream>>>(x, w_off, b_off, off);
    k_ostats<<<20, 256, 0, stream>>>(off, ostats);
    k_main<<<256, 256, 0, stream>>>(x, off, ostats, g_gn_off, b_gn_off, wT, b_dsc,
                                    out, csum);
    k_fin<<<1, 256, 0, stream>>>(csum, g_gn, b_gn, gnp);
    k_norm<<<B * C * HW / 4 / 256, 256, 0, stream>>>(out, gnp);
}

// Round 2
// 287.247 us; speedup vs baseline: 1.8135x; 1.8135x over previous
//
#include <hip/hip_runtime.h>
#include <hip/hip_bf16.h>
#include <math.h>

#define B 4
#define C 64
#define H 128
#define W 128
#define KK 9
#define CENTER 4
#define NOFF 10          // offset channels needed (0..8 + ch9 for GN group-4 stats)
#define HW (H*W)         // 16384

typedef __attribute__((ext_vector_type(8))) short short8;   // 8 x bf16 (4 VGPRs)
typedef __attribute__((ext_vector_type(4))) float f4;       // MFMA C/D frag

// ---------------- workspace layout (in floats) ----------------
#define OFF_OFF    0                       // B*NOFF*HW = 655360
#define OFF_OSTATS 655360                  // B*5*2 = 40 (+ pad to 64)
#define OFF_WB     655424                  // KK*C*C ushorts = 18432 floats
#define OFF_CSUM   673856                  // B*C*2 = 512
#define OFF_GNP    674368                  // B*C*2 = 512
// total 674880 floats = 2.70 MB

__device__ __forceinline__ unsigned bf16pack(float a, float b) {
    unsigned ua = __builtin_bit_cast(unsigned, a);
    unsigned ub = __builtin_bit_cast(unsigned, b);
    ua = (ua + 0x7fffu + ((ua >> 16) & 1u)) >> 16;          // RNE
    ub = (ub + 0x7fffu + ((ub >> 16) & 1u));
    return (ua & 0xffffu) | (ub & 0xffff0000u);
}

// ---- K0: w_dsc [co][ci][k] fp32 -> wb [k][co][ci] bf16 ----
__global__ __launch_bounds__(256) void k_cvtw(const float* __restrict__ w,
                                              unsigned short* __restrict__ wb) {
    int idx = blockIdx.x * 256 + threadIdx.x;
    if (idx < KK * C * C) {
        int k  = idx >> 12;
        int r  = idx & 4095;
        int co = r >> 6;
        int ci = r & 63;
        unsigned u = __builtin_bit_cast(unsigned, w[(co * C + ci) * KK + k]);
        u = (u + 0x7fffu + ((u >> 16) & 1u)) >> 16;
        wb[idx] = (unsigned short)u;
    }
}

// ---- K1: 3x3 SAME conv, x(64ch) -> off(10ch), +bias. 2-way co-split ----
__global__ __launch_bounds__(256) void k_offconv(const float* __restrict__ x,
                                                 const float* __restrict__ w_off,
                                                 const float* __restrict__ b_off,
                                                 float* __restrict__ off) {
    int bid  = blockIdx.x;           // 512 blocks: jh(2) x b(4) x ty(8) x tx(8)
    int jh   = bid >> 8;             // output-channel half: j0 = 5*jh
    int rest = bid & 255;
    int b  = rest >> 6;
    int ty = (rest >> 3) & 7, tx = rest & 7;
    int h0 = ty * 16, w0 = tx * 16;
    int tid = threadIdx.x;
    int lh = tid >> 4, lw = tid & 15;
    int j0 = jh * 5;

    __shared__ float lx[16 * 18 * 18];   // [ci_local][y][x], 20.7 KB

    float acc[5];
#pragma unroll
    for (int j = 0; j < 5; j++) acc[j] = 0.f;

    for (int cc = 0; cc < 4; cc++) {     // 4 chunks of 16 input channels
        __syncthreads();
        for (int i = tid; i < 16 * 324; i += 256) {
            int ci = i / 324;
            int r  = i - ci * 324;
            int y  = r / 18;
            int xx = r - y * 18;
            int gy = h0 + y - 1, gx = w0 + xx - 1;
            float v = 0.f;
            if (gy >= 0 && gy < H && gx >= 0 && gx < W)
                v = x[(((b * C) + (cc * 16 + ci)) * H + gy) * W + gx];
            lx[i] = v;
        }
        __syncthreads();

        for (int cl = 0; cl < 16; cl++) {
            int ci = cc * 16 + cl;
            float xv[9];
#pragma unroll
            for (int ky = 0; ky < 3; ky++)
#pragma unroll
                for (int kx = 0; kx < 3; kx++)
                    xv[ky * 3 + kx] = lx[(cl * 18 + lh + ky) * 18 + lw + kx];
#pragma unroll
            for (int j = 0; j < 5; j++) {
                const float* wp = w_off + ((j0 + j) * C + ci) * 9;  // uniform -> s_load
#pragma unroll
                for (int t = 0; t < 9; t++) acc[j] += wp[t] * xv[t];
            }
        }
    }

    int h = h0 + lh, w = w0 + lw;
#pragma unroll
    for (int j = 0; j < 5; j++)
        off[((b * NOFF + j0 + j) * H + h) * W + w] = acc[j] + b_off[j0 + j];
}

// ---- K2: GN stats for offsets: groups of 2 channels, 20 (b,g) blocks ----
__global__ __launch_bounds__(256) void k_ostats(const float* __restrict__ off,
                                                float* __restrict__ ostats) {
    int b = blockIdx.x / 5, g = blockIdx.x % 5;
    int tid = threadIdx.x;
    float s = 0.f, s2 = 0.f;
    const float* p0 = off + ((size_t)(b * NOFF + 2 * g) * HW);
    for (int i = tid; i < 2 * HW; i += 256) {
        float v = p0[i];
        s += v; s2 += v * v;
    }
    __shared__ float rs[256], rq[256];
    rs[tid] = s; rq[tid] = s2;
    __syncthreads();
    for (int st = 128; st > 0; st >>= 1) {
        if (tid < st) { rs[tid] += rs[tid + st]; rq[tid] += rq[tid + st]; }
        __syncthreads();
    }
    if (tid == 0) {
        float n = 2.f * HW;
        float mean = rs[0] / n;
        float var  = rq[0] / n - mean * mean;
        ostats[(b * 5 + g) * 2]     = mean;
        ostats[(b * 5 + g) * 2 + 1] = rsqrtf(var + 1e-5f);
    }
}

// ---- K4: fused tanh+cumsum+resample + MFMA 9x1 conv + GN partials ----
// Block = one (b,h) row: 128 pixels x 64 co. 256 threads = 4 waves.
// K-loop: 9 chunks (one per tap k), chunk K = 64 (all ci).
// LDS samples: bf16 [p][ci], row = 64 bf16 = 8 x 16B groups, group index
// XOR-swizzled by (p&7) -> conflict-free b128 read/write.
__global__ __launch_bounds__(256, 2) void k_main(const float* __restrict__ x,
                                                 const float* __restrict__ off,
                                                 const float* __restrict__ ostats,
                                                 const float* __restrict__ g_gn_off,
                                                 const float* __restrict__ b_gn_off,
                                                 const unsigned short* __restrict__ wb,
                                                 const float* __restrict__ b_dsc,
                                                 float* __restrict__ outp,
                                                 float* __restrict__ csum) {
    __shared__ float smem[64 * 132];                 // 33792 B (epilogue view)
    unsigned short* sbuf = (unsigned short*)smem;    // sample view [128][64] bf16
    unsigned* sw = (unsigned*)smem;

    int bid = blockIdx.x;          // 512: b(4) x h(128)
    int b = bid >> 7;
    int h = bid & 127;
    int tid  = threadIdx.x;
    int wid  = tid >> 6;
    int lane = tid & 63;

    // sample-role assignment
    int p   = ((wid & 1) << 6) + lane;   // pixel 0..127
    int ci0 = (wid >> 1) << 5;           // 0 or 32

    // ---- offsets -> per-pixel y coordinates (9 taps) ----
    float yoff[KK];
    {
        float v[KK];
#pragma unroll
        for (int j = 0; j < KK; j++) {
            float o = off[((b * NOFF + j) * H + h) * W + p];
            int g = j >> 1;
            float mean = ostats[(b * 5 + g) * 2];
            float rstd = ostats[(b * 5 + g) * 2 + 1];
            v[j] = tanhf((o - mean) * rstd * g_gn_off[j] + b_gn_off[j]);
        }
        yoff[CENTER] = 0.f;
        float run = 0.f;
#pragma unroll
        for (int k = CENTER - 1; k >= 0; k--) { run += v[k]; yoff[k] = run; }
        run = 0.f;
#pragma unroll
        for (int k = CENTER + 1; k < KK; k++) { run += v[k]; yoff[k] = run; }
    }
    int   y0a[KK];
    float wya[KK];
#pragma unroll
    for (int k = 0; k < KK; k++) {
        float yc = fminf(fmaxf((float)h + yoff[k], 0.f), (float)(H - 1));
        float fy = floorf(yc);
        y0a[k] = (int)fy;
        wya[k] = yc - fy;
    }

    f4 acc[2][4];
#pragma unroll
    for (int pp = 0; pp < 2; pp++)
#pragma unroll
        for (int ct = 0; ct < 4; ct++) acc[pp][ct] = 0;

    const float* xb = x + (size_t)b * C * HW + (size_t)ci0 * HW;
    int pt0 = wid * 2;               // this wave's 2 p-tiles
    int lm = lane & 15, qd = lane >> 4;

#pragma unroll
    for (int k = 0; k < KK; k++) {
        // ---- sample phase: 32 ci for my pixel ----
        int xi = min(max(p + k - CENTER, 0), W - 1);
        const float* pa = xb + (size_t)y0a[k] * W + xi;
        const float* pb = xb + (size_t)min(y0a[k] + 1, H - 1) * W + xi;
        float fw = wya[k];
#pragma unroll
        for (int g = 0; g < 4; g++) {
            unsigned pk[4];
#pragma unroll
            for (int e = 0; e < 4; e++) {
                int c0 = g * 8 + e * 2;
                float v00 = pa[(size_t)c0 * HW];
                float v10 = pb[(size_t)c0 * HW];
                float v01 = pa[(size_t)(c0 + 1) * HW];
                float v11 = pb[(size_t)(c0 + 1) * HW];
                float s0 = v00 + fw * (v10 - v00);
                float s1 = v01 + fw * (v11 - v01);
                pk[e] = bf16pack(s0, s1);
            }
            int G  = (ci0 >> 3) + g;          // 16B group 0..7 within row
            int Gs = G ^ (p & 7);             // XOR swizzle
            *(uint4*)(sw + (size_t)p * 32 + Gs * 4) =
                make_uint4(pk[0], pk[1], pk[2], pk[3]);
        }
        __syncthreads();

        // ---- MFMA phase ----
        const unsigned short* wk = wb + k * (C * C);
        short8 bfr[2][4];
#pragma unroll
        for (int s = 0; s < 2; s++)
#pragma unroll
            for (int ct = 0; ct < 4; ct++)
                bfr[s][ct] = *(const short8*)(wk + (ct * 16 + lm) * 64 + s * 32 + qd * 8);
        short8 afr[2][2];
#pragma unroll
        for (int pp = 0; pp < 2; pp++) {
            int prow = (pt0 + pp) * 16 + lm;
#pragma unroll
            for (int s = 0; s < 2; s++) {
                int G  = s * 4 + qd;
                int Gs = G ^ (prow & 7);
                afr[pp][s] = *(const short8*)(sbuf + (size_t)prow * 64 + Gs * 8);
            }
        }
#pragma unroll
        for (int s = 0; s < 2; s++)
#pragma unroll
            for (int pp = 0; pp < 2; pp++)
#pragma unroll
                for (int ct = 0; ct < 4; ct++)
                    acc[pp][ct] = __builtin_amdgcn_mfma_f32_16x16x32_bf16(
                        afr[pp][s], bfr[s][ct], acc[pp][ct], 0, 0, 0);
        __syncthreads();
    }

    // ---- epilogue: stage [co][p] in LDS (stride 132), +bias ----
#pragma unroll
    for (int pp = 0; pp < 2; pp++)
#pragma unroll
        for (int ct = 0; ct < 4; ct++) {
            int co = ct * 16 + lm;
            float bias = b_dsc[co];
#pragma unroll
            for (int r = 0; r < 4; r++) {
                int prow = (pt0 + pp) * 16 + qd * 4 + r;
                smem[co * 132 + prow] = acc[pp][ct][r] + bias;
            }
        }
    __syncthreads();

    // coalesced store + GN partial sums
    int co = tid >> 2, q = tid & 3;
    const float* srow = smem + co * 132 + q * 32;
    float* orow = outp + ((size_t)(b * C + co)) * HW + h * W + q * 32;
    float sv = 0.f, sq = 0.f;
#pragma unroll
    for (int i = 0; i < 8; i++) {
        f4 t = *(const f4*)(srow + i * 4);
        *(f4*)(orow + i * 4) = t;
        sv += t[0] + t[1] + t[2] + t[3];
        sq += t[0]*t[0] + t[1]*t[1] + t[2]*t[2] + t[3]*t[3];
    }
    sv += __shfl_xor(sv, 1); sv += __shfl_xor(sv, 2);
    sq += __shfl_xor(sq, 1); sq += __shfl_xor(sq, 2);
    if (q == 0) {
        atomicAdd(&csum[(b * C + co) * 2],     sv);
        atomicAdd(&csum[(b * C + co) * 2 + 1], sq);
    }
}

// ---- K5: finalize GN params ----
__global__ __launch_bounds__(256) void k_fin(const float* __restrict__ csum,
                                             const float* __restrict__ g_gn,
                                             const float* __restrict__ b_gn,
                                             float* __restrict__ gnp) {
    int t = threadIdx.x;             // 256 == B*C
    int b = t >> 6, co = t & 63;
    int grp = co >> 2;
    float S = 0.f, S2 = 0.f;
#pragma unroll
    for (int c2 = 0; c2 < 4; c2++) {
        S  += csum[(b * C + grp * 4 + c2) * 2];
        S2 += csum[(b * C + grp * 4 + c2) * 2 + 1];
    }
    float n = 4.f * HW;
    float mean = S / n;
    float var  = S2 / n - mean * mean;
    float rstd = rsqrtf(var + 1e-5f);
    float sc = rstd * g_gn[co];
    gnp[(b * C + co) * 2]     = sc;
    gnp[(b * C + co) * 2 + 1] = b_gn[co] - mean * sc;
}

// ---- K6: in-place GN apply + ReLU ----
__global__ __launch_bounds__(256) void k_norm(float* __restrict__ outp,
                                              const float* __restrict__ gnp) {
    int idx = blockIdx.x * 256 + threadIdx.x;
    float4* ptr = (float4*)outp;
    float4 vv = ptr[idx];
    int bc = (idx * 4) >> 14;
    float sc = gnp[bc * 2], sh = gnp[bc * 2 + 1];
    vv.x = fmaxf(vv.x * sc + sh, 0.f);
    vv.y = fmaxf(vv.y * sc + sh, 0.f);
    vv.z = fmaxf(vv.z * sc + sh, 0.f);
    vv.w = fmaxf(vv.w * sc + sh, 0.f);
    ptr[idx] = vv;
}

extern "C" void kernel_launch(void* const* d_in, const int* in_sizes, int n_in,
                              void* d_out, int out_size, void* d_ws, size_t ws_size,
                              hipStream_t stream) {
    const float* x        = (const float*)d_in[0];
    const float* w_off    = (const float*)d_in[1];
    const float* b_off    = (const float*)d_in[2];
    const float* g_gn_off = (const float*)d_in[3];
    const float* b_gn_off = (const float*)d_in[4];
    const float* w_dsc    = (const float*)d_in[5];
    const float* b_dsc    = (const float*)d_in[6];
    const float* g_gn     = (const float*)d_in[7];
    const float* b_gn     = (const float*)d_in[8];
    float* out = (float*)d_out;
    float* ws  = (float*)d_ws;

    float*          off    = ws + OFF_OFF;
    float*          ostats = ws + OFF_OSTATS;
    unsigned short* wbp    = (unsigned short*)(ws + OFF_WB);
    float*          csum   = ws + OFF_CSUM;
    float*          gnp    = ws + OFF_GNP;

    hipMemsetAsync(csum, 0, 2 * B * C * sizeof(float), stream);
    k_cvtw<<<(KK * C * C + 255) / 256, 256, 0, stream>>>(w_dsc, wbp);
    k_offconv<<<512, 256, 0, stream>>>(x, w_off, b_off, off);
    k_ostats<<<20, 256, 0, stream>>>(off, ostats);
    k_main<<<B * H, 256, 0, stream>>>(x, off, ostats, g_gn_off, b_gn_off, wbp,
                                      b_dsc, out, csum);
    k_fin<<<1, 256, 0, stream>>>(csum, g_gn, b_gn, gnp);
    k_norm<<<B * C * HW / 4 / 256, 256, 0, stream>>>(out, gnp);
}

// Round 3
// 223.615 us; speedup vs baseline: 2.3295x; 1.2846x over previous
//
#include <hip/hip_runtime.h>
#include <hip/hip_bf16.h>
#include <math.h>

#define B 4
#define C 64
#define H 128
#define W 128
#define KK 9
#define CENTER 4
#define NOFF 10          // offset channels needed (0..8 + ch9 for GN group-4 stats)
#define HW (H*W)         // 16384

typedef __attribute__((ext_vector_type(8))) short short8;   // 8 x bf16 (4 VGPRs)
typedef __attribute__((ext_vector_type(4))) float f4;       // MFMA C/D frag

// ---------------- workspace layout (in floats) ----------------
#define OFF_OFF    0                       // B*NOFF*HW = 655360
#define OFF_WB     655360                  // KK*C*C ushorts = 18432 floats
#define OFF_CSUM   673792                  // B*C*2 = 512   (zeroed)
#define OFF_OSUM   674304                  // B*5*2 = 40 -> 64 (zeroed, same memset)
#define OFF_GNP    674368                  // B*C*2 = 512
// total 674880 floats = 2.70 MB

__device__ __forceinline__ unsigned bf16pack(float a, float b) {
    // round-half-up to bf16, pack a->low16, b->high16 (1 add + 1 add + 1 perm)
    unsigned ua = __builtin_bit_cast(unsigned, a) + 0x8000u;
    unsigned ub = __builtin_bit_cast(unsigned, b) + 0x8000u;
    return __builtin_amdgcn_perm(ub, ua, 0x07060302);
}

__device__ __forceinline__ float fast_tanh(float x) {
    float e = __expf(2.f * x);                      // v_exp_f32
    return 1.f - 2.f * __builtin_amdgcn_rcpf(e + 1.f);
}

// ---- K0: w_dsc [co][ci][k] fp32 -> wb [k][co][ci] bf16 ----
__global__ __launch_bounds__(256) void k_cvtw(const float* __restrict__ w,
                                              unsigned short* __restrict__ wb) {
    int idx = blockIdx.x * 256 + threadIdx.x;
    if (idx < KK * C * C) {
        int k  = idx >> 12;
        int r  = idx & 4095;
        int co = r >> 6;
        int ci = r & 63;
        unsigned u = __builtin_bit_cast(unsigned, w[(co * C + ci) * KK + k]);
        u = (u + 0x7fffu + ((u >> 16) & 1u)) >> 16;
        wb[idx] = (unsigned short)u;
    }
}

// ---- K1: 3x3 SAME conv, x(64ch) -> off(10ch), +bias. 2-way co-split ----
__global__ __launch_bounds__(256) void k_offconv(const float* __restrict__ x,
                                                 const float* __restrict__ w_off,
                                                 const float* __restrict__ b_off,
                                                 float* __restrict__ off) {
    int bid  = blockIdx.x;           // 512 blocks: jh(2) x b(4) x ty(8) x tx(8)
    int jh   = bid >> 8;             // output-channel half: j0 = 5*jh
    int rest = bid & 255;
    int b  = rest >> 6;
    int ty = (rest >> 3) & 7, tx = rest & 7;
    int h0 = ty * 16, w0 = tx * 16;
    int tid = threadIdx.x;
    int lh = tid >> 4, lw = tid & 15;
    int j0 = jh * 5;

    __shared__ float lx[16 * 18 * 18];   // [ci_local][y][x], 20.7 KB

    float acc[5];
#pragma unroll
    for (int j = 0; j < 5; j++) acc[j] = 0.f;

    for (int cc = 0; cc < 4; cc++) {     // 4 chunks of 16 input channels
        __syncthreads();
        for (int i = tid; i < 16 * 324; i += 256) {
            int ci = i / 324;
            int r  = i - ci * 324;
            int y  = r / 18;
            int xx = r - y * 18;
            int gy = h0 + y - 1, gx = w0 + xx - 1;
            float v = 0.f;
            if (gy >= 0 && gy < H && gx >= 0 && gx < W)
                v = x[(((b * C) + (cc * 16 + ci)) * H + gy) * W + gx];
            lx[i] = v;
        }
        __syncthreads();

        for (int cl = 0; cl < 16; cl++) {
            int ci = cc * 16 + cl;
            float xv[9];
#pragma unroll
            for (int ky = 0; ky < 3; ky++)
#pragma unroll
                for (int kx = 0; kx < 3; kx++)
                    xv[ky * 3 + kx] = lx[(cl * 18 + lh + ky) * 18 + lw + kx];
#pragma unroll
            for (int j = 0; j < 5; j++) {
                const float* wp = w_off + ((j0 + j) * C + ci) * 9;  // uniform -> s_load
#pragma unroll
                for (int t = 0; t < 9; t++) acc[j] += wp[t] * xv[t];
            }
        }
    }

    int h = h0 + lh, w = w0 + lw;
#pragma unroll
    for (int j = 0; j < 5; j++)
        off[((b * NOFF + j0 + j) * H + h) * W + w] = acc[j] + b_off[j0 + j];
}

// ---- K2: offset GN raw sums (partial, atomic): 80 blocks ----
__global__ __launch_bounds__(256) void k_ostats(const float* __restrict__ off,
                                                float* __restrict__ osum) {
    int blk = blockIdx.x;            // 80 = 20 (b,g) x 4 quarter
    int q  = blk & 3;
    int bg = blk >> 2;
    int b = bg / 5, g = bg - 5 * b;
    const float4* p4 = (const float4*)(off + (size_t)(b * NOFF + 2 * g) * HW) + q * 2048;
    int tid = threadIdx.x;
    float s = 0.f, s2 = 0.f;
#pragma unroll
    for (int it = 0; it < 8; it++) {
        float4 v = p4[tid + it * 256];
        s  += v.x + v.y + v.z + v.w;
        s2 += v.x * v.x + v.y * v.y + v.z * v.z + v.w * v.w;
    }
#pragma unroll
    for (int o = 32; o >= 1; o >>= 1) {
        s += __shfl_xor(s, o); s2 += __shfl_xor(s2, o);
    }
    __shared__ float rs[8];
    int wid = tid >> 6, lane = tid & 63;
    if (lane == 0) { rs[wid] = s; rs[wid + 4] = s2; }
    __syncthreads();
    if (tid == 0) {
        atomicAdd(&osum[bg * 2],     rs[0] + rs[1] + rs[2] + rs[3]);
        atomicAdd(&osum[bg * 2 + 1], rs[4] + rs[5] + rs[6] + rs[7]);
    }
}

// ---- K4: fused tanh+cumsum+resample + MFMA 9x1 conv + GN partials ----
// Block = one (b,h) row, XCD-swizzled: bid&7 = XCD gets a contiguous 16-row
// chunk per batch -> x band (25 rows x 4 b x 32 KB = 3.2 MB) resident in L2.
__global__ __launch_bounds__(256, 2) void k_main(const float* __restrict__ x,
                                                 const float* __restrict__ off,
                                                 const float* __restrict__ osum,
                                                 const float* __restrict__ g_gn_off,
                                                 const float* __restrict__ b_gn_off,
                                                 const unsigned short* __restrict__ wb,
                                                 const float* __restrict__ b_dsc,
                                                 float* __restrict__ outp,
                                                 float* __restrict__ csum) {
    __shared__ float smem[64 * 132];                 // 33792 B (epilogue view)
    unsigned short* sbuf = (unsigned short*)smem;    // sample view [128][64] bf16
    unsigned* sw = (unsigned*)smem;

    int bid = blockIdx.x;          // 512: xcd(8) x [b(4) x hc(16)]
    int xcd = bid & 7;
    int i   = bid >> 3;
    int b   = i >> 4;
    int h   = (xcd << 4) | (i & 15);
    int tid  = threadIdx.x;
    int wid  = tid >> 6;
    int lane = tid & 63;

    // sample-role assignment
    int p   = ((wid & 1) << 6) + lane;   // pixel 0..127
    int ci0 = (wid >> 1) << 5;           // 0 or 32

    // ---- offset GN stats (from raw sums) ----
    float means[5], rstds[5];
    const float inv_n = 1.f / (2.f * HW);
#pragma unroll
    for (int g = 0; g < 5; g++) {
        float s  = osum[(b * 5 + g) * 2];
        float s2 = osum[(b * 5 + g) * 2 + 1];
        float mean = s * inv_n;
        float var  = s2 * inv_n - mean * mean;
        means[g] = mean;
        rstds[g] = rsqrtf(var + 1e-5f);
    }

    // ---- offsets -> per-pixel y coordinates (9 taps) ----
    float yoff[KK];
    {
        float v[KK];
#pragma unroll
        for (int j = 0; j < KK; j++) {
            float o = off[((b * NOFF + j) * H + h) * W + p];
            int g = j >> 1;
            v[j] = fast_tanh((o - means[g]) * rstds[g] * g_gn_off[j] + b_gn_off[j]);
        }
        yoff[CENTER] = 0.f;
        float run = 0.f;
#pragma unroll
        for (int k = CENTER - 1; k >= 0; k--) { run += v[k]; yoff[k] = run; }
        run = 0.f;
#pragma unroll
        for (int k = CENTER + 1; k < KK; k++) { run += v[k]; yoff[k] = run; }
    }
    int   y0a[KK];
    float wya[KK];
#pragma unroll
    for (int k = 0; k < KK; k++) {
        float yc = fminf(fmaxf((float)h + yoff[k], 0.f), (float)(H - 1));
        float fy = floorf(yc);
        y0a[k] = (int)fy;
        wya[k] = yc - fy;
    }

    f4 acc[2][4];
#pragma unroll
    for (int pp = 0; pp < 2; pp++)
#pragma unroll
        for (int ct = 0; ct < 4; ct++) acc[pp][ct] = 0;

    const float* xb = x + (size_t)b * C * HW + (size_t)ci0 * HW;
    int pt0 = wid * 2;               // this wave's 2 p-tiles
    int lm = lane & 15, qd = lane >> 4;

#pragma unroll
    for (int k = 0; k < KK; k++) {
        // ---- sample phase: 32 ci for my pixel ----
        int xi = min(max(p + k - CENTER, 0), W - 1);
        const float* pa = xb + (size_t)y0a[k] * W + xi;
        const float* pb = xb + (size_t)min(y0a[k] + 1, H - 1) * W + xi;
        float fw = wya[k];
#pragma unroll
        for (int g = 0; g < 4; g++) {
            unsigned pk[4];
#pragma unroll
            for (int e = 0; e < 4; e++) {
                int c0 = g * 8 + e * 2;
                float v00 = pa[(size_t)c0 * HW];
                float v10 = pb[(size_t)c0 * HW];
                float v01 = pa[(size_t)(c0 + 1) * HW];
                float v11 = pb[(size_t)(c0 + 1) * HW];
                float s0 = v00 + fw * (v10 - v00);
                float s1 = v01 + fw * (v11 - v01);
                pk[e] = bf16pack(s0, s1);
            }
            int G  = (ci0 >> 3) + g;          // 16B group 0..7 within row
            int Gs = G ^ (p & 7);             // XOR swizzle
            *(uint4*)(sw + (size_t)p * 32 + Gs * 4) =
                make_uint4(pk[0], pk[1], pk[2], pk[3]);
        }
        __syncthreads();

        // ---- MFMA phase ----
        const unsigned short* wk = wb + k * (C * C);
        short8 bfr[2][4];
#pragma unroll
        for (int s = 0; s < 2; s++)
#pragma unroll
            for (int ct = 0; ct < 4; ct++)
                bfr[s][ct] = *(const short8*)(wk + (ct * 16 + lm) * 64 + s * 32 + qd * 8);
        short8 afr[2][2];
#pragma unroll
        for (int pp = 0; pp < 2; pp++) {
            int prow = (pt0 + pp) * 16 + lm;
#pragma unroll
            for (int s = 0; s < 2; s++) {
                int G  = s * 4 + qd;
                int Gs = G ^ (prow & 7);
                afr[pp][s] = *(const short8*)(sbuf + (size_t)prow * 64 + Gs * 8);
            }
        }
#pragma unroll
        for (int s = 0; s < 2; s++)
#pragma unroll
            for (int pp = 0; pp < 2; pp++)
#pragma unroll
                for (int ct = 0; ct < 4; ct++)
                    acc[pp][ct] = __builtin_amdgcn_mfma_f32_16x16x32_bf16(
                        afr[pp][s], bfr[s][ct], acc[pp][ct], 0, 0, 0);
        __syncthreads();
    }

    // ---- epilogue: stage [co][p] in LDS (stride 132), +bias ----
#pragma unroll
    for (int pp = 0; pp < 2; pp++)
#pragma unroll
        for (int ct = 0; ct < 4; ct++) {
            int co = ct * 16 + lm;
            float bias = b_dsc[co];
#pragma unroll
            for (int r = 0; r < 4; r++) {
                int prow = (pt0 + pp) * 16 + qd * 4 + r;
                smem[co * 132 + prow] = acc[pp][ct][r] + bias;
            }
        }
    __syncthreads();

    // coalesced store + GN partial sums
    int co = tid >> 2, q = tid & 3;
    const float* srow = smem + co * 132 + q * 32;
    float* orow = outp + ((size_t)(b * C + co)) * HW + h * W + q * 32;
    float sv = 0.f, sq = 0.f;
#pragma unroll
    for (int i2 = 0; i2 < 8; i2++) {
        f4 t = *(const f4*)(srow + i2 * 4);
        *(f4*)(orow + i2 * 4) = t;
        sv += t[0] + t[1] + t[2] + t[3];
        sq += t[0]*t[0] + t[1]*t[1] + t[2]*t[2] + t[3]*t[3];
    }
    sv += __shfl_xor(sv, 1); sv += __shfl_xor(sv, 2);
    sq += __shfl_xor(sq, 1); sq += __shfl_xor(sq, 2);
    if (q == 0) {
        atomicAdd(&csum[(b * C + co) * 2],     sv);
        atomicAdd(&csum[(b * C + co) * 2 + 1], sq);
    }
}

// ---- K5: finalize GN params ----
__global__ __launch_bounds__(256) void k_fin(const float* __restrict__ csum,
                                             const float* __restrict__ g_gn,
                                             const float* __restrict__ b_gn,
                                             float* __restrict__ gnp) {
    int t = threadIdx.x;             // 256 == B*C
    int b = t >> 6, co = t & 63;
    int grp = co >> 2;
    float S = 0.f, S2 = 0.f;
#pragma unroll
    for (int c2 = 0; c2 < 4; c2++) {
        S  += csum[(b * C + grp * 4 + c2) * 2];
        S2 += csum[(b * C + grp * 4 + c2) * 2 + 1];
    }
    float n = 4.f * HW;
    float mean = S / n;
    float var  = S2 / n - mean * mean;
    float rstd = rsqrtf(var + 1e-5f);
    float sc = rstd * g_gn[co];
    gnp[(b * C + co) * 2]     = sc;
    gnp[(b * C + co) * 2 + 1] = b_gn[co] - mean * sc;
}

// ---- K6: in-place GN apply + ReLU ----
__global__ __launch_bounds__(256) void k_norm(float* __restrict__ outp,
                                              const float* __restrict__ gnp) {
    int idx = blockIdx.x * 256 + threadIdx.x;
    float4* ptr = (float4*)outp;
    float4 vv = ptr[idx];
    int bc = (idx * 4) >> 14;
    float sc = gnp[bc * 2], sh = gnp[bc * 2 + 1];
    vv.x = fmaxf(vv.x * sc + sh, 0.f);
    vv.y = fmaxf(vv.y * sc + sh, 0.f);
    vv.z = fmaxf(vv.z * sc + sh, 0.f);
    vv.w = fmaxf(vv.w * sc + sh, 0.f);
    ptr[idx] = vv;
}

extern "C" void kernel_launch(void* const* d_in, const int* in_sizes, int n_in,
                              void* d_out, int out_size, void* d_ws, size_t ws_size,
                              hipStream_t stream) {
    const float* x        = (const float*)d_in[0];
    const float* w_off    = (const float*)d_in[1];
    const float* b_off    = (const float*)d_in[2];
    const float* g_gn_off = (const float*)d_in[3];
    const float* b_gn_off = (const float*)d_in[4];
    const float* w_dsc    = (const float*)d_in[5];
    const float* b_dsc    = (const float*)d_in[6];
    const float* g_gn     = (const float*)d_in[7];
    const float* b_gn     = (const float*)d_in[8];
    float* out = (float*)d_out;
    float* ws  = (float*)d_ws;

    float*          off    = ws + OFF_OFF;
    unsigned short* wbp    = (unsigned short*)(ws + OFF_WB);
    float*          csum   = ws + OFF_CSUM;
    float*          osum   = ws + OFF_OSUM;
    float*          gnp    = ws + OFF_GNP;

    hipMemsetAsync(csum, 0, (512 + 64) * sizeof(float), stream);  // csum+osum
    k_cvtw<<<(KK * C * C + 255) / 256, 256, 0, stream>>>(w_dsc, wbp);
    k_offconv<<<512, 256, 0, stream>>>(x, w_off, b_off, off);
    k_ostats<<<80, 256, 0, stream>>>(off, osum);
    k_main<<<B * H, 256, 0, stream>>>(x, off, osum, g_gn_off, b_gn_off, wbp,
                                      b_dsc, out, csum);
    k_fin<<<1, 256, 0, stream>>>(csum, g_gn, b_gn, gnp);
    k_norm<<<B * C * HW / 4 / 256, 256, 0, stream>>>(out, gnp);
}

// Round 4
// 195.692 us; speedup vs baseline: 2.6619x; 1.1427x over previous
//
#include <hip/hip_runtime.h>
#include <hip/hip_bf16.h>
#include <math.h>

#define B 4
#define C 64
#define H 128
#define W 128
#define KK 9
#define CENTER 4
#define HW (H*W)         // 16384

typedef __attribute__((ext_vector_type(8))) short short8;   // 8 x bf16 (4 VGPRs)
typedef __attribute__((ext_vector_type(4))) float f4;       // MFMA C/D frag

// ---------------- workspace layout (in floats) ----------------
#define OFF_OFF    0                       // off: B*10*HW = 655360
#define OFF_XB     655360                  // xb: B*HW*64 bf16 = 2097152 floats
#define OFF_WB     2752512                 // wb: KK*C*C bf16 = 18432 floats
#define OFF_WOB    2770944                 // wob: 9*16*64 bf16 = 4608 floats
#define OFF_CSUM   2775552                 // B*C*2 = 512 (zeroed)
#define OFF_OSUM   2776064                 // B*5*2 -> 64 (zeroed, same memset)
// total 2776128 floats = 11.1 MB

__device__ __forceinline__ unsigned bf16pack(float a, float b) {
    // round-half-up to bf16; a->low16, b->high16
    unsigned ua = __builtin_bit_cast(unsigned, a) + 0x8000u;
    unsigned ub = __builtin_bit_cast(unsigned, b) + 0x8000u;
    return __builtin_amdgcn_perm(ub, ua, 0x07060302);
}

__device__ __forceinline__ unsigned lerp_pack(unsigned a, unsigned b, float fw) {
    // a,b each hold 2 bf16 (lo,hi); y-lerp both, repack
    float alo = __builtin_bit_cast(float, a << 16);
    float ahi = __builtin_bit_cast(float, a & 0xffff0000u);
    float blo = __builtin_bit_cast(float, b << 16);
    float bhi = __builtin_bit_cast(float, b & 0xffff0000u);
    float slo = alo + fw * (blo - alo);
    float shi = ahi + fw * (bhi - ahi);
    return bf16pack(slo, shi);
}

__device__ __forceinline__ float fast_tanh(float x) {
    float e = __expf(2.f * x);
    return 1.f - 2.f * __builtin_amdgcn_rcpf(e + 1.f);
}

// ---- K0: weight converts.
// A: w_dsc [co][ci][k] fp32 -> wb [k][co][ci] bf16            (36864)
// B: w_off [j][ci][ky][kx] fp32 -> wob [tap][j16][ci] bf16    (9216, j>=10 -> 0)
__global__ __launch_bounds__(256) void k_cvtw(const float* __restrict__ w_dsc,
                                              const float* __restrict__ w_off,
                                              unsigned short* __restrict__ wb,
                                              unsigned short* __restrict__ wob) {
    int idx = blockIdx.x * 256 + threadIdx.x;
    if (idx < KK * C * C) {
        int k  = idx >> 12;
        int r  = idx & 4095;
        int co = r >> 6;
        int ci = r & 63;
        unsigned u = __builtin_bit_cast(unsigned, w_dsc[(co * C + ci) * KK + k]);
        u = (u + 0x7fffu + ((u >> 16) & 1u)) >> 16;
        wb[idx] = (unsigned short)u;
    } else if (idx < KK * C * C + 9 * 16 * 64) {
        int r   = idx - KK * C * C;
        int tap = r >> 10;
        int j   = (r >> 6) & 15;
        int ci  = r & 63;
        float v = (j < 10) ? w_off[(j * C + ci) * 9 + tap] : 0.f;
        unsigned u = __builtin_bit_cast(unsigned, v);
        u = (u + 0x7fffu + ((u >> 16) & 1u)) >> 16;
        wob[r] = (unsigned short)u;
    }
}

// ---- K1: transpose x [b][ci][h][w] fp32 -> xb [b][h][w][ci] bf16 ----
__global__ __launch_bounds__(256) void k_cvtx(const float* __restrict__ x,
                                              unsigned short* __restrict__ xb) {
    __shared__ float lt[64 * 33];
    int bid = blockIdx.x;          // 512: b(4) x h(128)
    int b = bid >> 7, h = bid & 127;
    int tid = threadIdx.x;
    int ciA = tid >> 2, gA = tid & 3;          // phase A roles
    int wlB = tid >> 3, cgB = tid & 7;         // phase B roles

    for (int c = 0; c < 4; c++) {
        int w0 = c * 32;
        __syncthreads();
        {
            const float* src = x + ((size_t)(b * C + ciA) * HW) + h * W + w0 + gA * 8;
            float4 v0 = *(const float4*)src;
            float4 v1 = *(const float4*)(src + 4);
            float* d = lt + ciA * 33 + gA * 8;
            d[0] = v0.x; d[1] = v0.y; d[2] = v0.z; d[3] = v0.w;
            d[4] = v1.x; d[5] = v1.y; d[6] = v1.z; d[7] = v1.w;
        }
        __syncthreads();
        {
            unsigned u[4];
#pragma unroll
            for (int i = 0; i < 4; i++) {
                float lo = lt[(cgB * 8 + 2 * i)     * 33 + wlB];
                float hi = lt[(cgB * 8 + 2 * i + 1) * 33 + wlB];
                u[i] = bf16pack(lo, hi);
            }
            *(uint4*)(xb + ((size_t)((b * H + h) * W + w0 + wlB)) * 64 + cgB * 8) =
                make_uint4(u[0], u[1], u[2], u[3]);
        }
    }
}

// ---- K2: offset conv via MFMA implicit GEMM + fused GN raw sums ----
// Block = (b,h) row (XCD-swizzled). LDS: 3 halo rows of xb in
// [plane=r*8+G][wp 0..129][8ci] layout (wp=0/129 are zero pad).
__global__ __launch_bounds__(256, 2) void k_offconv(const unsigned short* __restrict__ xb,
                                                    const unsigned short* __restrict__ wob,
                                                    const float* __restrict__ b_off,
                                                    float* __restrict__ off,
                                                    float* __restrict__ osum) {
    __shared__ uint4 xr[3120];     // 24 planes * 130 = 49920 B
    int bid = blockIdx.x;          // 512: xcd(8) x [b(4) x hc(16)]
    int xcd = bid & 7;
    int i   = bid >> 3;
    int b   = i >> 4;
    int h   = (xcd << 4) | (i & 15);
    int tid  = threadIdx.x;
    int wid  = tid >> 6;
    int lane = tid & 63;
    int lm = lane & 15, qd = lane >> 4;

    // ---- stage 3 rows (zero-padded) ----
    for (int t = tid; t < 3120; t += 256) {
        int plane = t / 130;
        int wp    = t - plane * 130;
        int r = plane >> 3, G = plane & 7;
        int y = h - 1 + r;
        uint4 v = make_uint4(0, 0, 0, 0);
        if ((unsigned)y < (unsigned)H && wp >= 1 && wp <= W)
            v = *(const uint4*)(xb + ((size_t)((b * H + y) * W + wp - 1)) * 64 + G * 8);
        xr[t] = v;
    }
    __syncthreads();

    const unsigned short* sb = (const unsigned short*)xr;
    f4 acc[2];
    acc[0] = 0; acc[1] = 0;

#pragma unroll
    for (int ky = 0; ky < 3; ky++)
#pragma unroll
        for (int kx = 0; kx < 3; kx++) {
            int tap = ky * 3 + kx;
            short8 bfr[2];
#pragma unroll
            for (int s = 0; s < 2; s++)
                bfr[s] = *(const short8*)(wob + (tap * 16 + lm) * 64 + s * 32 + qd * 8);
#pragma unroll
            for (int pp = 0; pp < 2; pp++) {
                int wp = (wid * 2 + pp) * 16 + lm + kx;
#pragma unroll
                for (int s = 0; s < 2; s++) {
                    short8 afr = *(const short8*)(sb +
                        ((size_t)((ky * 8 + s * 4 + qd) * 130 + wp)) * 8);
                    acc[pp] = __builtin_amdgcn_mfma_f32_16x16x32_bf16(afr, bfr[s],
                                                                      acc[pp], 0, 0, 0);
                }
            }
        }

    __syncthreads();
    float* red = (float*)xr;
    float bo = b_off[lm];
    float sv = 0.f, sq = 0.f;
#pragma unroll
    for (int pp = 0; pp < 2; pp++)
#pragma unroll
        for (int r = 0; r < 4; r++) {
            float val = acc[pp][r] + bo;
            if (lm < 10) {
                int p = (wid * 2 + pp) * 16 + qd * 4 + r;
                off[((size_t)(b * 10 + lm) * H + h) * W + p] = val;
                sv += val; sq += val * val;
            }
        }
    sv += __shfl_xor(sv, 16); sv += __shfl_xor(sv, 32);
    sq += __shfl_xor(sq, 16); sq += __shfl_xor(sq, 32);
    if (lane < 16 && lm < 10) {
        red[(wid * 10 + lm) * 2]     = sv;
        red[(wid * 10 + lm) * 2 + 1] = sq;
    }
    __syncthreads();
    if (tid < 20) {
        int j = tid >> 1, comp = tid & 1;
        float s = red[j * 2 + comp] + red[(10 + j) * 2 + comp] +
                  red[(20 + j) * 2 + comp] + red[(30 + j) * 2 + comp];
        atomicAdd(&osum[(b * 5 + (j >> 1)) * 2 + comp], s);
    }
}

// ---- K3: fused tanh+cumsum+resample + MFMA 9x1 conv + GN partials ----
// Block = (b,h,half-row): 64 pixels x 64 co. 1024 blocks, XCD-swizzled.
__global__ __launch_bounds__(256, 4) void k_main(const unsigned short* __restrict__ xb,
                                                 const float* __restrict__ off,
                                                 const float* __restrict__ osum,
                                                 const float* __restrict__ g_gn_off,
                                                 const float* __restrict__ b_gn_off,
                                                 const unsigned short* __restrict__ wb,
                                                 const float* __restrict__ b_dsc,
                                                 float* __restrict__ outp,
                                                 float* __restrict__ csum) {
    __shared__ float smem[64 * 68];                  // 17408 B (epilogue view)
    unsigned short* sbuf = (unsigned short*)smem;    // sample view: [8 planes][66][8ci]
    uint4* sv4 = (uint4*)smem;

    int bid = blockIdx.x;          // 1024: xcd(8) x [b(4) x hc(16) x half(2)]
    int xcd  = bid & 7;
    int i    = bid >> 3;
    int b    = i >> 5;
    int rest = i & 31;
    int h    = (xcd << 4) | (rest >> 1);
    int p0   = (rest & 1) << 6;
    int tid  = threadIdx.x;
    int wid  = tid >> 6;
    int lane = tid & 63;
    int lm = lane & 15, qd = lane >> 4;

    int pl  = tid & 63;            // local pixel for sampling
    int ps  = p0 + pl;             // global pixel
    int ci0 = wid << 4;            // 16 ci per thread

    // ---- offset GN stats ----
    float means[5], rstds[5];
    const float inv_n = 1.f / (2.f * HW);
#pragma unroll
    for (int g = 0; g < 5; g++) {
        float s  = osum[(b * 5 + g) * 2];
        float s2 = osum[(b * 5 + g) * 2 + 1];
        float mean = s * inv_n;
        float var  = s2 * inv_n - mean * mean;
        means[g] = mean;
        rstds[g] = rsqrtf(var + 1e-5f);
    }

    // ---- offsets -> per-pixel y coords ----
    float yoff[KK];
    {
        float v[KK];
#pragma unroll
        for (int j = 0; j < KK; j++) {
            float o = off[((size_t)(b * 10 + j) * H + h) * W + ps];
            int g = j >> 1;
            v[j] = fast_tanh((o - means[g]) * rstds[g] * g_gn_off[j] + b_gn_off[j]);
        }
        yoff[CENTER] = 0.f;
        float run = 0.f;
#pragma unroll
        for (int k = CENTER - 1; k >= 0; k--) { run += v[k]; yoff[k] = run; }
        run = 0.f;
#pragma unroll
        for (int k = CENTER + 1; k < KK; k++) { run += v[k]; yoff[k] = run; }
    }

    f4 acc[4];
#pragma unroll
    for (int ct = 0; ct < 4; ct++) acc[ct] = 0;

#pragma unroll
    for (int k = 0; k < KK; k++) {
        // ---- sample phase: 16 ci for my pixel ----
        float yc = fminf(fmaxf((float)h + yoff[k], 0.f), (float)(H - 1));
        float fy = floorf(yc);
        int y0 = (int)fy;
        int y1 = min(y0 + 1, H - 1);
        float fw = yc - fy;
        int xi = min(max(ps + k - CENTER, 0), W - 1);
        const unsigned short* pa = xb + ((size_t)((b * H + y0) * W + xi)) * 64 + ci0;
        const unsigned short* pb = xb + ((size_t)((b * H + y1) * W + xi)) * 64 + ci0;
        uint4 a0 = *(const uint4*)pa;
        uint4 a1 = *(const uint4*)(pa + 8);
        uint4 b0 = *(const uint4*)pb;
        uint4 b1 = *(const uint4*)(pb + 8);
        uint4 r0, r1;
        r0.x = lerp_pack(a0.x, b0.x, fw); r0.y = lerp_pack(a0.y, b0.y, fw);
        r0.z = lerp_pack(a0.z, b0.z, fw); r0.w = lerp_pack(a0.w, b0.w, fw);
        r1.x = lerp_pack(a1.x, b1.x, fw); r1.y = lerp_pack(a1.y, b1.y, fw);
        r1.z = lerp_pack(a1.z, b1.z, fw); r1.w = lerp_pack(a1.w, b1.w, fw);
        int G0 = wid * 2;
        sv4[(G0)     * 66 + pl] = r0;
        sv4[(G0 + 1) * 66 + pl] = r1;
        __syncthreads();

        // ---- MFMA phase: wave wid owns p-tile wid ----
        const unsigned short* wk = wb + k * (C * C);
#pragma unroll
        for (int s = 0; s < 2; s++) {
            short8 afr = *(const short8*)(sbuf +
                ((size_t)((s * 4 + qd) * 66 + wid * 16 + lm)) * 8);
#pragma unroll
            for (int ct = 0; ct < 4; ct++) {
                short8 bfr = *(const short8*)(wk + (ct * 16 + lm) * 64 + s * 32 + qd * 8);
                acc[ct] = __builtin_amdgcn_mfma_f32_16x16x32_bf16(afr, bfr,
                                                                  acc[ct], 0, 0, 0);
            }
        }
        __syncthreads();
    }

    // ---- epilogue: stage [co][p] (stride 68), +bias ----
#pragma unroll
    for (int ct = 0; ct < 4; ct++) {
        int co = ct * 16 + lm;
        float bias = b_dsc[co];
#pragma unroll
        for (int r = 0; r < 4; r++) {
            int p = wid * 16 + qd * 4 + r;
            smem[co * 68 + p] = acc[ct][r] + bias;
        }
    }
    __syncthreads();

    // coalesced store + GN partial sums
    int co = tid >> 2, q = tid & 3;
    const float* srow = smem + co * 68 + q * 16;
    float* orow = outp + ((size_t)(b * C + co)) * HW + h * W + p0 + q * 16;
    float sv = 0.f, sq = 0.f;
#pragma unroll
    for (int i2 = 0; i2 < 4; i2++) {
        f4 t = *(const f4*)(srow + i2 * 4);
        *(f4*)(orow + i2 * 4) = t;
        sv += t[0] + t[1] + t[2] + t[3];
        sq += t[0]*t[0] + t[1]*t[1] + t[2]*t[2] + t[3]*t[3];
    }
    sv += __shfl_xor(sv, 1); sv += __shfl_xor(sv, 2);
    sq += __shfl_xor(sq, 1); sq += __shfl_xor(sq, 2);
    if (q == 0) {
        atomicAdd(&csum[(b * C + co) * 2],     sv);
        atomicAdd(&csum[(b * C + co) * 2 + 1], sq);
    }
}

// ---- K4: GN finalize (per block) + apply + ReLU ----
__global__ __launch_bounds__(256) void k_norm(float* __restrict__ outp,
                                              const float* __restrict__ csum,
                                              const float* __restrict__ g_gn,
                                              const float* __restrict__ b_gn) {
    int bid = blockIdx.x;           // 4096: bc(256) x 16
    int bc = bid >> 4;
    int b = bc >> 6, co = bc & 63;
    int grp = co >> 2;
    float S = 0.f, S2 = 0.f;
#pragma unroll
    for (int c2 = 0; c2 < 4; c2++) {
        S  += csum[(b * C + grp * 4 + c2) * 2];
        S2 += csum[(b * C + grp * 4 + c2) * 2 + 1];
    }
    float n = 4.f * HW;
    float mean = S / n;
    float var  = S2 / n - mean * mean;
    float rstd = rsqrtf(var + 1e-5f);
    float sc = rstd * g_gn[co];
    float sh = b_gn[co] - mean * sc;

    int idx = bid * 256 + threadIdx.x;
    float4* ptr = (float4*)outp;
    float4 vv = ptr[idx];
    vv.x = fmaxf(vv.x * sc + sh, 0.f);
    vv.y = fmaxf(vv.y * sc + sh, 0.f);
    vv.z = fmaxf(vv.z * sc + sh, 0.f);
    vv.w = fmaxf(vv.w * sc + sh, 0.f);
    ptr[idx] = vv;
}

extern "C" void kernel_launch(void* const* d_in, const int* in_sizes, int n_in,
                              void* d_out, int out_size, void* d_ws, size_t ws_size,
                              hipStream_t stream) {
    const float* x        = (const float*)d_in[0];
    const float* w_off    = (const float*)d_in[1];
    const float* b_off    = (const float*)d_in[2];
    const float* g_gn_off = (const float*)d_in[3];
    const float* b_gn_off = (const float*)d_in[4];
    const float* w_dsc    = (const float*)d_in[5];
    const float* b_dsc    = (const float*)d_in[6];
    const float* g_gn     = (const float*)d_in[7];
    const float* b_gn     = (const float*)d_in[8];
    float* out = (float*)d_out;
    float* ws  = (float*)d_ws;

    float*          off  = ws + OFF_OFF;
    unsigned short* xbp  = (unsigned short*)(ws + OFF_XB);
    unsigned short* wbp  = (unsigned short*)(ws + OFF_WB);
    unsigned short* wobp = (unsigned short*)(ws + OFF_WOB);
    float*          csum = ws + OFF_CSUM;
    float*          osum = ws + OFF_OSUM;

    hipMemsetAsync(csum, 0, (512 + 64) * sizeof(float), stream);
    k_cvtw<<<180, 256, 0, stream>>>(w_dsc, w_off, wbp, wobp);
    k_cvtx<<<B * H, 256, 0, stream>>>(x, xbp);
    k_offconv<<<B * H, 256, 0, stream>>>(xbp, wobp, b_off, off, osum);
    k_main<<<2 * B * H, 256, 0, stream>>>(xbp, off, osum, g_gn_off, b_gn_off,
                                          wbp, b_dsc, out, csum);
    k_norm<<<B * C * HW / 4 / 256, 256, 0, stream>>>(out, csum, g_gn, b_gn);
}

// Round 5
// 191.457 us; speedup vs baseline: 2.7208x; 1.0221x over previous
//
#include <hip/hip_runtime.h>
#include <hip/hip_bf16.h>
#include <math.h>

#define B 4
#define C 64
#define H 128
#define W 128
#define KK 9
#define CENTER 4
#define HW (H*W)         // 16384
#define HP 130           // padded height
#define WP 130           // padded width

typedef __attribute__((ext_vector_type(8))) short short8;   // 8 x bf16 (4 VGPRs)
typedef __attribute__((ext_vector_type(4))) float f4;       // MFMA C/D frag

// ---------------- workspace layout (in floats) ----------------
#define OFF_OFF    0                       // off: B*10*HW = 655360
#define OFF_XB     655360                  // xb: B*130*130*64 bf16 = 2163200 floats
#define OFF_WB     2818560                 // wb: KK*C*C bf16 = 18432 floats
#define OFF_WOB    2836992                 // wob: 9*16*64 bf16 = 4608 floats
#define OFF_CSUM   2841600                 // B*C*2 = 512 (zeroed)
#define OFF_OSUM   2842112                 // B*5*2 -> 64 (zeroed, same memset)
// total 2842176 floats = 11.4 MB

__device__ __forceinline__ unsigned bf16pack(float a, float b) {
    // round-half-up to bf16; a->low16, b->high16
    unsigned ua = __builtin_bit_cast(unsigned, a) + 0x8000u;
    unsigned ub = __builtin_bit_cast(unsigned, b) + 0x8000u;
    return __builtin_amdgcn_perm(ub, ua, 0x07060302);
}

__device__ __forceinline__ unsigned lerp_pack(unsigned a, unsigned b, float fw) {
    // a,b each hold 2 bf16 (lo,hi); y-lerp both, repack
    float alo = __builtin_bit_cast(float, a << 16);
    float ahi = __builtin_bit_cast(float, a & 0xffff0000u);
    float blo = __builtin_bit_cast(float, b << 16);
    float bhi = __builtin_bit_cast(float, b & 0xffff0000u);
    float slo = alo + fw * (blo - alo);
    float shi = ahi + fw * (bhi - ahi);
    return bf16pack(slo, shi);
}

__device__ __forceinline__ float fast_tanh(float x) {
    float e = __expf(2.f * x);
    return 1.f - 2.f * __builtin_amdgcn_rcpf(e + 1.f);
}

// ---- K0: weight converts.
// A: w_dsc [co][ci][k] fp32 -> wb [k][co][ci] bf16            (36864)
// B: w_off [j][ci][ky][kx] fp32 -> wob [tap][j16][ci] bf16    (9216, j>=10 -> 0)
__global__ __launch_bounds__(256) void k_cvtw(const float* __restrict__ w_dsc,
                                              const float* __restrict__ w_off,
                                              unsigned short* __restrict__ wb,
                                              unsigned short* __restrict__ wob) {
    int idx = blockIdx.x * 256 + threadIdx.x;
    if (idx < KK * C * C) {
        int k  = idx >> 12;
        int r  = idx & 4095;
        int co = r >> 6;
        int ci = r & 63;
        unsigned u = __builtin_bit_cast(unsigned, w_dsc[(co * C + ci) * KK + k]);
        u = (u + 0x7fffu + ((u >> 16) & 1u)) >> 16;
        wb[idx] = (unsigned short)u;
    } else if (idx < KK * C * C + 9 * 16 * 64) {
        int r   = idx - KK * C * C;
        int tap = r >> 10;
        int j   = (r >> 6) & 15;
        int ci  = r & 63;
        float v = (j < 10) ? w_off[(j * C + ci) * 9 + tap] : 0.f;
        unsigned u = __builtin_bit_cast(unsigned, v);
        u = (u + 0x7fffu + ((u >> 16) & 1u)) >> 16;
        wob[r] = (unsigned short)u;
    }
}

// ---- K1: transpose x [b][ci][h][w] fp32 -> xb [b][hp][wp][ci] bf16 (zero-pad) ----
__global__ __launch_bounds__(256) void k_cvtx(const float* __restrict__ x,
                                              unsigned short* __restrict__ xb) {
    int bid = blockIdx.x;          // 512 interior + 8 border-row blocks
    int tid = threadIdx.x;
    if (bid >= B * H) {            // zero rows hp=0,129
        int r = bid - B * H;
        int b = r >> 1, which = r & 1;
        unsigned short* dst = xb + ((size_t)(b * HP + which * (HP - 1)) * WP) * 64;
        for (int t = tid; t < WP * 64 / 8; t += 256)
            *(uint4*)(dst + t * 8) = make_uint4(0, 0, 0, 0);
        return;
    }
    __shared__ float lt[64 * 33];
    int b = bid >> 7, h = bid & 127;
    int ciA = tid >> 2, gA = tid & 3;          // phase A roles
    int wlB = tid >> 3, cgB = tid & 7;         // phase B roles

    // zero cols wp=0,129 of this row
    if (tid < 16) {
        int which = tid >> 3, q = tid & 7;
        *(uint4*)(xb + (((size_t)(b * HP + h + 1) * WP) + which * (WP - 1)) * 64 + q * 8)
            = make_uint4(0, 0, 0, 0);
    }

    for (int c = 0; c < 4; c++) {
        int w0 = c * 32;
        __syncthreads();
        {
            const float* src = x + ((size_t)(b * C + ciA) * HW) + h * W + w0 + gA * 8;
            float4 v0 = *(const float4*)src;
            float4 v1 = *(const float4*)(src + 4);
            float* d = lt + ciA * 33 + gA * 8;
            d[0] = v0.x; d[1] = v0.y; d[2] = v0.z; d[3] = v0.w;
            d[4] = v1.x; d[5] = v1.y; d[6] = v1.z; d[7] = v1.w;
        }
        __syncthreads();
        {
            unsigned u[4];
#pragma unroll
            for (int i = 0; i < 4; i++) {
                float lo = lt[(cgB * 8 + 2 * i)     * 33 + wlB];
                float hi = lt[(cgB * 8 + 2 * i + 1) * 33 + wlB];
                u[i] = bf16pack(lo, hi);
            }
            *(uint4*)(xb + ((size_t)((b * HP + h + 1) * WP + w0 + wlB + 1)) * 64 + cgB * 8) =
                make_uint4(u[0], u[1], u[2], u[3]);
        }
    }
}

// ---- K2: offset conv via MFMA, barrier-free K-loop (A-frags from global) ----
// Block = (b,h) row, XCD-swizzled. Wave owns 2 p-tiles x 16 j.
__global__ __launch_bounds__(256, 4) void k_offconv(const unsigned short* __restrict__ xb,
                                                    const unsigned short* __restrict__ wob,
                                                    const float* __restrict__ b_off,
                                                    float* __restrict__ off,
                                                    float* __restrict__ osum) {
    __shared__ float red[80];      // [wid*? ] 4 waves x 10 j x 2
    int bid = blockIdx.x;          // 512: xcd(8) x [b(4) x hc(16)]
    int xcd = bid & 7;
    int i   = bid >> 3;
    int b   = i >> 4;
    int h   = (xcd << 4) | (i & 15);
    int tid  = threadIdx.x;
    int wid  = tid >> 6;
    int lane = tid & 63;
    int lm = lane & 15, qd = lane >> 4;

    f4 acc[2];
    acc[0] = 0; acc[1] = 0;

    const unsigned short* xrow = xb + ((size_t)(b * HP + h) * WP) * 64;  // hp = h+ky
#pragma unroll
    for (int ky = 0; ky < 3; ky++)
#pragma unroll
        for (int kx = 0; kx < 3; kx++) {
            int tap = ky * 3 + kx;
            short8 bfr[2];
#pragma unroll
            for (int s = 0; s < 2; s++)
                bfr[s] = *(const short8*)(wob + (tap * 16 + lm) * 64 + s * 32 + qd * 8);
#pragma unroll
            for (int pp = 0; pp < 2; pp++) {
                int wp = (wid * 2 + pp) * 16 + lm + kx;      // padded wp = p-1+kx+1
#pragma unroll
                for (int s = 0; s < 2; s++) {
                    short8 afr = *(const short8*)(xrow +
                        ((size_t)(ky * WP + wp)) * 64 + s * 32 + qd * 8);
                    acc[pp] = __builtin_amdgcn_mfma_f32_16x16x32_bf16(afr, bfr[s],
                                                                      acc[pp], 0, 0, 0);
                }
            }
        }

    // epilogue: bias, store (f4 per p-tile), GN raw partial sums
    float bo = b_off[lm];          // j = lm (only lm<10 meaningful)
    float sv = 0.f, sq = 0.f;
#pragma unroll
    for (int pp = 0; pp < 2; pp++) {
        f4 v;
#pragma unroll
        for (int r = 0; r < 4; r++) {
            v[r] = acc[pp][r] + bo;
            sv += v[r]; sq += v[r] * v[r];
        }
        if (lm < 10) {
            int p = (wid * 2 + pp) * 16 + qd * 4;
            *(f4*)(off + ((size_t)(b * 10 + lm) * H + h) * W + p) = v;
        }
    }
    sv += __shfl_xor(sv, 16); sv += __shfl_xor(sv, 32);
    sq += __shfl_xor(sq, 16); sq += __shfl_xor(sq, 32);
    if (lane < 16 && lm < 10) {
        red[(wid * 10 + lm) * 2]     = sv;
        red[(wid * 10 + lm) * 2 + 1] = sq;
    }
    __syncthreads();
    if (tid < 20) {
        int j = tid >> 1, comp = tid & 1;
        float s = red[j * 2 + comp] + red[(10 + j) * 2 + comp] +
                  red[(20 + j) * 2 + comp] + red[(30 + j) * 2 + comp];
        atomicAdd(&osum[(b * 5 + (j >> 1)) * 2 + comp], s);
    }
}

// ---- K3: fused tanh+cumsum+resample + MFMA 9x1 conv, barrier-free K-loop ----
// Block = (b,h,half): 64 pixels x 64 co, wave owns 16-pixel tile x 64 co.
__global__ __launch_bounds__(256, 4) void k_main(const unsigned short* __restrict__ xb,
                                                 const float* __restrict__ off,
                                                 const float* __restrict__ osum,
                                                 const float* __restrict__ g_gn_off,
                                                 const float* __restrict__ b_gn_off,
                                                 const unsigned short* __restrict__ wb,
                                                 const float* __restrict__ b_dsc,
                                                 float* __restrict__ outp,
                                                 float* __restrict__ csum) {
    __shared__ float red[512];     // [wid][ct][lm][2]

    int bid = blockIdx.x;          // 1024: xcd(8) x [b(4) x hc(16) x half(2)]
    int xcd  = bid & 7;
    int i    = bid >> 3;
    int b    = i >> 5;
    int rest = i & 31;
    int h    = (xcd << 4) | (rest >> 1);
    int p0   = (rest & 1) << 6;
    int tid  = threadIdx.x;
    int wid  = tid >> 6;
    int lane = tid & 63;
    int lm = lane & 15, qd = lane >> 4;

    int ps = p0 + wid * 16 + lm;   // this thread's pixel (dup x4 across quads)

    // ---- offset GN stats ----
    float means[5], rstds[5];
    const float inv_n = 1.f / (2.f * HW);
#pragma unroll
    for (int g = 0; g < 5; g++) {
        float s  = osum[(b * 5 + g) * 2];
        float s2 = osum[(b * 5 + g) * 2 + 1];
        float mean = s * inv_n;
        float var  = s2 * inv_n - mean * mean;
        means[g] = mean;
        rstds[g] = rsqrtf(var + 1e-5f);
    }

    // ---- offsets -> per-pixel sampling coords (element offsets into xb) ----
    int   ofsA[KK], ofsB[KK];
    float wya[KK];
    {
        float v[KK];
#pragma unroll
        for (int j = 0; j < KK; j++) {
            float o = off[((size_t)(b * 10 + j) * H + h) * W + ps];
            int g = j >> 1;
            v[j] = fast_tanh((o - means[g]) * rstds[g] * g_gn_off[j] + b_gn_off[j]);
        }
        float yoff[KK];
        yoff[CENTER] = 0.f;
        float run = 0.f;
#pragma unroll
        for (int k = CENTER - 1; k >= 0; k--) { run += v[k]; yoff[k] = run; }
        run = 0.f;
#pragma unroll
        for (int k = CENTER + 1; k < KK; k++) { run += v[k]; yoff[k] = run; }
#pragma unroll
        for (int k = 0; k < KK; k++) {
            float yc = fminf(fmaxf((float)h + yoff[k], 0.f), (float)(H - 1));
            float fy = floorf(yc);
            int y0 = (int)fy;
            int y1 = min(y0 + 1, H - 1);
            wya[k] = yc - fy;
            int xi = min(max(ps + k - CENTER, 0), W - 1);
            ofsA[k] = ((b * HP + y0 + 1) * WP + xi + 1) * 64;
            ofsB[k] = ((b * HP + y1 + 1) * WP + xi + 1) * 64;
        }
    }

    f4 acc[4];
#pragma unroll
    for (int ct = 0; ct < 4; ct++) acc[ct] = 0;

#pragma unroll
    for (int k = 0; k < KK; k++) {
        const unsigned short* wk = wb + k * (C * C);
        float fw = wya[k];
#pragma unroll
        for (int s = 0; s < 2; s++) {
            int co_ofs = s * 32 + qd * 8;
            uint4 a = *(const uint4*)(xb + ofsA[k] + co_ofs);
            uint4 bb = *(const uint4*)(xb + ofsB[k] + co_ofs);
            uint4 r;
            r.x = lerp_pack(a.x, bb.x, fw);
            r.y = lerp_pack(a.y, bb.y, fw);
            r.z = lerp_pack(a.z, bb.z, fw);
            r.w = lerp_pack(a.w, bb.w, fw);
            short8 afr = __builtin_bit_cast(short8, r);
#pragma unroll
            for (int ct = 0; ct < 4; ct++) {
                short8 bfr = *(const short8*)(wk + (ct * 16 + lm) * 64 + co_ofs);
                acc[ct] = __builtin_amdgcn_mfma_f32_16x16x32_bf16(afr, bfr,
                                                                  acc[ct], 0, 0, 0);
            }
        }
    }

    // ---- epilogue: +bias, direct f4 stores (64B/co segments), GN partials ----
#pragma unroll
    for (int ct = 0; ct < 4; ct++) {
        int co = ct * 16 + lm;
        float bias = b_dsc[co];
        f4 v;
        float sv = 0.f, sq = 0.f;
#pragma unroll
        for (int r = 0; r < 4; r++) {
            v[r] = acc[ct][r] + bias;
            sv += v[r]; sq += v[r] * v[r];
        }
        *(f4*)(outp + ((size_t)(b * C + co)) * HW + h * W + p0 + wid * 16 + qd * 4) = v;
        sv += __shfl_xor(sv, 16); sv += __shfl_xor(sv, 32);
        sq += __shfl_xor(sq, 16); sq += __shfl_xor(sq, 32);
        if (lane < 16) {
            red[((wid * 4 + ct) * 16 + lm) * 2]     = sv;
            red[((wid * 4 + ct) * 16 + lm) * 2 + 1] = sq;
        }
    }
    __syncthreads();
    if (tid < 128) {
        int co = tid >> 1, comp = tid & 1;
        int ct = co >> 4, lmr = co & 15;
        float s = 0.f;
#pragma unroll
        for (int w2 = 0; w2 < 4; w2++)
            s += red[((w2 * 4 + ct) * 16 + lmr) * 2 + comp];
        atomicAdd(&csum[(b * C + co) * 2 + comp], s);
    }
}

// ---- K4: GN finalize (per block) + apply + ReLU ----
__global__ __launch_bounds__(256) void k_norm(float* __restrict__ outp,
                                              const float* __restrict__ csum,
                                              const float* __restrict__ g_gn,
                                              const float* __restrict__ b_gn) {
    int bid = blockIdx.x;           // 4096: bc(256) x 16
    int bc = bid >> 4;
    int b = bc >> 6, co = bc & 63;
    int grp = co >> 2;
    float S = 0.f, S2 = 0.f;
#pragma unroll
    for (int c2 = 0; c2 < 4; c2++) {
        S  += csum[(b * C + grp * 4 + c2) * 2];
        S2 += csum[(b * C + grp * 4 + c2) * 2 + 1];
    }
    float n = 4.f * HW;
    float mean = S / n;
    float var  = S2 / n - mean * mean;
    float rstd = rsqrtf(var + 1e-5f);
    float sc = rstd * g_gn[co];
    float sh = b_gn[co] - mean * sc;

    int idx = bid * 256 + threadIdx.x;
    float4* ptr = (float4*)outp;
    float4 vv = ptr[idx];
    vv.x = fmaxf(vv.x * sc + sh, 0.f);
    vv.y = fmaxf(vv.y * sc + sh, 0.f);
    vv.z = fmaxf(vv.z * sc + sh, 0.f);
    vv.w = fmaxf(vv.w * sc + sh, 0.f);
    ptr[idx] = vv;
}

extern "C" void kernel_launch(void* const* d_in, const int* in_sizes, int n_in,
                              void* d_out, int out_size, void* d_ws, size_t ws_size,
                              hipStream_t stream) {
    const float* x        = (const float*)d_in[0];
    const float* w_off    = (const float*)d_in[1];
    const float* b_off    = (const float*)d_in[2];
    const float* g_gn_off = (const float*)d_in[3];
    const float* b_gn_off = (const float*)d_in[4];
    const float* w_dsc    = (const float*)d_in[5];
    const float* b_dsc    = (const float*)d_in[6];
    const float* g_gn     = (const float*)d_in[7];
    const float* b_gn     = (const float*)d_in[8];
    float* out = (float*)d_out;
    float* ws  = (float*)d_ws;

    float*          off  = ws + OFF_OFF;
    unsigned short* xbp  = (unsigned short*)(ws + OFF_XB);
    unsigned short* wbp  = (unsigned short*)(ws + OFF_WB);
    unsigned short* wobp = (unsigned short*)(ws + OFF_WOB);
    float*          csum = ws + OFF_CSUM;
    float*          osum = ws + OFF_OSUM;

    hipMemsetAsync(csum, 0, (512 + 64) * sizeof(float), stream);
    k_cvtw<<<180, 256, 0, stream>>>(w_dsc, w_off, wbp, wobp);
    k_cvtx<<<B * H + 8, 256, 0, stream>>>(x, xbp);
    k_offconv<<<B * H, 256, 0, stream>>>(xbp, wobp, b_off, off, osum);
    k_main<<<2 * B * H, 256, 0, stream>>>(xbp, off, osum, g_gn_off, b_gn_off,
                                          wbp, b_dsc, out, csum);
    k_norm<<<B * C * HW / 4 / 256, 256, 0, stream>>>(out, csum, g_gn, b_gn);
}